// Round 17
// baseline (274.371 us; speedup 1.0000x reference)
//
#include <hip/hip_runtime.h>

// Problem dims (fixed by setup_inputs)
#define Bb 8
#define Tt 2048
#define Hh 1024
#define Kk 256
#define Vv 256
#define Oo 1024
#define CC 64   // chunk length
#define NC 32   // chunks per batch (Tt/CC)

typedef __attribute__((ext_vector_type(8))) __bf16 bf16x8;
typedef __attribute__((ext_vector_type(4))) float f32x4;

__device__ __forceinline__ unsigned short f2b(float f) {
  unsigned u = __float_as_uint(f);
  u = (u + 0x7FFFu + ((u >> 16) & 1u)) >> 16;
  return (unsigned short)u;
}
__device__ __forceinline__ float b2f(unsigned short u) {
  return __uint_as_float(((unsigned)u) << 16);
}
__device__ __forceinline__ void gload_lds16(const unsigned short* g, unsigned short* l) {
  __builtin_amdgcn_global_load_lds(
      (const __attribute__((address_space(1))) void*)g,
      (__attribute__((address_space(3))) void*)l, 16, 0, 0);
}

// ---------------- cast f32 -> bf16 (vectorized) ----------------
__global__ __launch_bounds__(256) void cast_bf16_kernel(const float* __restrict__ in,
                                                        unsigned short* __restrict__ out,
                                                        int n4) {
  int i = blockIdx.x * 256 + threadIdx.x;
  if (i >= n4) return;
  float4 v = ((const float4*)in)[i];
  ushort4 o;
  o.x = f2b(v.x); o.y = f2b(v.y); o.z = f2b(v.z); o.w = f2b(v.w);
  ((ushort4*)out)[i] = o;
}

// ---------------- transpose + cast (batched): W[z] (H x N) f32 -> WT (N x H) bf16 ----
__global__ __launch_bounds__(256) void transpose_cast4_kernel(
    const float* __restrict__ W0, const float* __restrict__ W1,
    const float* __restrict__ W2, const float* __restrict__ W3,
    unsigned short* __restrict__ WT, int H, int N) {
  __shared__ float tile[32][33];
  const int z = blockIdx.z;
  const float* W = z == 0 ? W0 : z == 1 ? W1 : z == 2 ? W2 : W3;
  unsigned short* WTo = WT + (size_t)z * N * H;
  int h0 = blockIdx.x * 32, n0 = blockIdx.y * 32;
  int tx = threadIdx.x & 31, ty = threadIdx.x >> 5;
  for (int r = ty; r < 32; r += 8)
    tile[r][tx] = W[(size_t)(h0 + r) * N + n0 + tx];
  __syncthreads();
  for (int r = ty; r < 32; r += 8)
    WTo[(size_t)(n0 + r) * H + h0 + tx] = f2b(tile[tx][r]);
}

__global__ __launch_bounds__(256) void transpose_cast_kernel(const float* __restrict__ W,
                                                             unsigned short* __restrict__ WT,
                                                             int H, int N) {
  __shared__ float tile[32][33];
  int h0 = blockIdx.x * 32, n0 = blockIdx.y * 32;
  int tx = threadIdx.x & 31, ty = threadIdx.x >> 5;
  for (int r = ty; r < 32; r += 8)
    tile[r][tx] = W[(size_t)(h0 + r) * N + n0 + tx];
  __syncthreads();
  for (int r = ty; r < 32; r += 8)
    WT[(size_t)(n0 + r) * H + h0 + tx] = f2b(tile[tx][r]);
}

// ---------------- WIDE GEMM: 128x256 tile, BK=64, 8 waves, round-10 cadence --------
// Staged volume = M*N*K*2*(1/128 + 1/256) = 0.79x of 128^2 tiling; per-wave gload
// depth 6/iter (vs 8), same swizzle (128B rows, chunk ^= row&7, pre-swizzled source).
// MODE 0: proj epilogue, one 256-wide output panel per block (q/sig-k/log2sig-g/vT),
//         LDS-staged coalesced writes in two 128-col halves.
// MODE 1: f32 out + bias, direct 64B-segment writes.
#define BM 128
#define BN 256
#define BK 64

template <int MODE>
__global__ __launch_bounds__(512, 4) void gemm_wide_kernel(
    const unsigned short* __restrict__ A, const unsigned short* __restrict__ Bt,
    const float* __restrict__ b0p, const float* __restrict__ b1p,
    const float* __restrict__ b2p, const float* __restrict__ b3p,
    float* __restrict__ Cf,
    unsigned short* __restrict__ O0, unsigned short* __restrict__ O1,
    unsigned short* __restrict__ O2, unsigned short* __restrict__ O3,
    int M, int N, int K) {
  // LDS: As 128x64 (16KB) + Bs 256x64 (32KB) = 48KB; first 32KB reused by epilogue.
  __shared__ __align__(16) unsigned short shbuf[24576];
  unsigned short* As = shbuf;           // 8192 shorts
  unsigned short* Bs = shbuf + 8192;    // 16384 shorts
  const int tid = threadIdx.x;
  const int lane = tid & 63, wid = tid >> 6;        // 8 waves
  const int wm = wid >> 2, wn = wid & 3;            // 2m x 4n; wave = 64x64 out
  // XCD-local mapping: XCD (lin&7) owns contiguous m-panels; n iterated fastest.
  const int lin = blockIdx.x + blockIdx.y * gridDim.x;
  const int xcd = lin & 7;
  const int jj = lin >> 3;
  const int mpg = gridDim.y >> 3;
  const int m0 = (xcd * mpg + jj / gridDim.x) * BM;
  const int n0 = (jj % gridDim.x) * BN;
  const int fr = lane & 15, fq = lane >> 4;
  // staging: per gload a wave writes 8 rows x 128B. Lane l -> row +(l>>3),
  // LDS 16B-chunk (l&7); global source chunk = (l&7) ^ (l>>3).
  const int srl = lane >> 3;
  const int scs = ((lane & 7) ^ srl) * 8;
  const unsigned short* gaBase = A + (size_t)(m0 + srl) * K + scs;
  const unsigned short* gbBase = Bt + (size_t)(n0 + srl) * K + scs;

  f32x4 acc[4][4] = {};
  const int nt = K / BK;
  for (int t = 0; t < nt; ++t) {
    const int k0 = t * BK;
    __syncthreads();  // previous iter's LDS reads done
    // A: 128 rows -> 2 gloads/wave; B: 256 rows -> 4 gloads/wave
#pragma unroll
    for (int inst = 0; inst < 2; ++inst) {
      const int rb = wid * 16 + inst * 8;
      gload_lds16(gaBase + (size_t)rb * K + k0, &As[rb * BK]);
    }
#pragma unroll
    for (int inst = 0; inst < 4; ++inst) {
      const int rb = wid * 32 + inst * 8;
      gload_lds16(gbBase + (size_t)rb * K + k0, &Bs[rb * BK]);
    }
    __syncthreads();  // staged data visible (drain hidden by co-resident waves)
#pragma unroll
    for (int ks = 0; ks < 2; ++ks) {
      bf16x8 af[4], bfv[4];
#pragma unroll
      for (int j = 0; j < 4; ++j) {
        const int R = wn * 64 + j * 16 + fr;
        const int ch = ((ks << 2) | fq) ^ (fr & 7);
        bfv[j] = *(const bf16x8*)&Bs[R * BK + ch * 8];
      }
#pragma unroll
      for (int i = 0; i < 4; ++i) {
        const int R = wm * 64 + i * 16 + fr;
        const int ch = ((ks << 2) | fq) ^ (fr & 7);
        af[i] = *(const bf16x8*)&As[R * BK + ch * 8];
      }
#pragma unroll
      for (int i = 0; i < 4; ++i)
#pragma unroll
        for (int j = 0; j < 4; ++j)
          acc[i][j] = __builtin_amdgcn_mfma_f32_16x16x32_bf16(af[i], bfv[j], acc[i][j], 0, 0, 0);
    }
  }

  if (MODE == 1) {
    // direct f32 writes: 16-lane clusters cover 64B segments
#pragma unroll
    for (int j = 0; j < 4; ++j) {
      const int n = n0 + wn * 64 + j * 16 + fr;
      const float bv = b0p[n];
#pragma unroll
      for (int i = 0; i < 4; ++i) {
        const int mb = m0 + wm * 64 + i * 16 + fq * 4;
#pragma unroll
        for (int r = 0; r < 4; ++r)
          Cf[(size_t)(mb + r) * N + n] = acc[i][j][r] + bv;
      }
    }
  } else {
    // LDS-staged epilogue in two 128-col halves (32KB stage region).
    const int sel = n0 >> 8;  // block covers exactly one 256-wide output panel
    const float* bp = sel == 0 ? b0p : sel == 1 ? b1p : sel == 2 ? b2p : b3p;
    unsigned short* Op = sel == 0 ? O0 : sel == 1 ? O1 : sel == 2 ? O2 : O3;
    for (int h = 0; h < 2; ++h) {
      __syncthreads();  // prior LDS users done
      if ((wn >> 1) == h) {  // waves holding cols [h*128, h*128+128)
#pragma unroll
        for (int j = 0; j < 4; ++j) {
          const int ncol = wn * 64 + j * 16 + fr;   // [0,256)
          const int cl = ncol - h * 128;            // [0,128)
          const float bv = bp[ncol];
#pragma unroll
          for (int i = 0; i < 4; ++i) {
#pragma unroll
            for (int r = 0; r < 4; ++r) {
              const int ml = wm * 64 + i * 16 + fq * 4 + r;
              const float x = acc[i][j][r] + bv;
              unsigned short us;
              if (sel == 0) {
                us = f2b(x);
              } else if (sel == 1) {
                us = f2b(1.f / (1.f + expf(-x)));
              } else if (sel == 2) {
                float e = exp2f(-x * 1.44269504f);
                float lg = -log2f(1.f + e);
                _Float16 hv = (_Float16)lg;
                __builtin_memcpy(&us, &hv, 2);
              } else {
                us = f2b(x);
              }
              if (sel == 3) {  // stage transposed: row=v(cl), col=t(ml)
                const int cm = (ml >> 3) ^ (cl & 15);
                shbuf[cl * 128 + cm * 8 + (ml & 7)] = us;
              } else {         // row=m(ml), col=n(cl)
                const int cn = (cl >> 3) ^ (ml & 15);
                shbuf[ml * 128 + cn * 8 + (cl & 7)] = us;
              }
            }
          }
        }
      }
      __syncthreads();
      // write: 128 rows x 256B; 4 threads/row, 4 x 16B stores each
      const int row = tid >> 2;
      const int q4 = tid & 3;
      if (sel == 3) {
        unsigned short* dst = O3 + ((size_t)(m0 >> 11) * Vv + h * 128 + row) * Tt +
                              (m0 & 2047) + q4 * 32;
#pragma unroll
        for (int ic = 0; ic < 4; ++ic) {
          const int chunk = q4 * 4 + ic;
          const int sc = chunk ^ (row & 15);
          *(uint4*)(dst + ic * 8) = *(const uint4*)&shbuf[row * 128 + sc * 8];
        }
      } else {
        unsigned short* dst = Op + (size_t)(m0 + row) * 256 + h * 128 + q4 * 32;
#pragma unroll
        for (int ic = 0; ic < 4; ++ic) {
          const int chunk = q4 * 4 + ic;
          const int sc = chunk ^ (row & 15);
          *(uint4*)(dst + ic * 8) = *(const uint4*)&shbuf[row * 128 + sc * 8];
        }
      }
    }
  }
}

// ---------------- fused prep+sgemm: per (b,c) task ----------------
__global__ __launch_bounds__(256) void prep_sgemm_kernel(
    const unsigned short* __restrict__ qb, const unsigned short* __restrict__ kb,
    const unsigned short* __restrict__ lgb, const unsigned short* __restrict__ vTb,
    unsigned short* __restrict__ q2b, unsigned short* __restrict__ qab,
    unsigned short* __restrict__ kab,
    float* __restrict__ LBb, float* __restrict__ Dendb,
    unsigned short* __restrict__ Sb) {
  __shared__ __align__(16) unsigned short khs[256][72];
  const int c = blockIdx.x, b = blockIdx.y;
  const int k = threadIdx.x;
  const int task = b * NC + c;
  const size_t rowbase = ((size_t)b * Tt + (size_t)c * CC) * Kk + k;
  float Ls = 0.f;
  float LBr[4];
#pragma unroll
  for (int gq = 0; gq < 4; ++gq) {
    LBr[gq] = Ls;
#pragma unroll
    for (int tt = 0; tt < 16; ++tt) {
      int t = gq * 16 + tt;
      _Float16 hv;
      __builtin_memcpy(&hv, &lgb[rowbase + (size_t)t * Kk], 2);
      Ls += (float)hv;
    }
  }
  const float Lend = Ls;
#pragma unroll
  for (int gq = 0; gq < 4; ++gq) LBb[(size_t)task * 1024 + gq * 256 + k] = LBr[gq];
  Dendb[task * 256 + k] = exp2f(Lend);
  float L = 0.f;
#pragma unroll
  for (int gq = 0; gq < 4; ++gq) {
    const float LBc = LBr[gq];
    unsigned kw[8];
#pragma unroll
    for (int tt = 0; tt < 16; ++tt) {
      int t = gq * 16 + tt;
      size_t off = rowbase + (size_t)t * Kk;
      _Float16 hv;
      __builtin_memcpy(&hv, &lgb[off], 2);
      L += (float)hv;
      float qv = b2f(qb[off]);
      float kv = b2f(kb[off]);
      q2b[off] = f2b(qv * exp2f(L));
      qab[off] = f2b(qv * exp2f(L - LBc));
      kab[off] = f2b(kv * exp2f(LBc - L));
      unsigned short kh = f2b(kv * exp2f(Lend - L));
      if (tt & 1) kw[tt >> 1] |= ((unsigned)kh) << 16;
      else        kw[tt >> 1] = kh;
    }
    uint4 u0; u0.x = kw[0]; u0.y = kw[1]; u0.z = kw[2]; u0.w = kw[3];
    uint4 u1; u1.x = kw[4]; u1.y = kw[5]; u1.z = kw[6]; u1.w = kw[7];
    *(uint4*)&khs[k][gq * 16] = u0;
    *(uint4*)&khs[k][gq * 16 + 8] = u1;
  }
  __syncthreads();
  const int tid = threadIdx.x, lane = tid & 63, w = tid >> 6;
  const int fr = lane & 15, fq = lane >> 4, fk = fq * 8;
  const unsigned short* vt = vTb + (size_t)b * (Vv * Tt) + (size_t)c * CC;
  for (int vb4 = 0; vb4 < 4; ++vb4) {
    f32x4 acc[4][4] = {};
#pragma unroll
    for (int ks = 0; ks < 2; ++ks) {
      bf16x8 af[4], bf[4];
#pragma unroll
      for (int i = 0; i < 4; ++i)
        af[i] = *(const bf16x8*)&khs[w * 64 + i * 16 + fr][ks * 32 + fk];
#pragma unroll
      for (int j = 0; j < 4; ++j)
        bf[j] = *(const bf16x8*)(vt + (size_t)(vb4 * 64 + j * 16 + fr) * Tt + ks * 32 + fk);
#pragma unroll
      for (int i = 0; i < 4; ++i)
#pragma unroll
        for (int j = 0; j < 4; ++j)
          acc[i][j] = __builtin_amdgcn_mfma_f32_16x16x32_bf16(af[i], bf[j], acc[i][j], 0, 0, 0);
    }
#pragma unroll
    for (int i = 0; i < 4; ++i)
#pragma unroll
      for (int j = 0; j < 4; ++j)
#pragma unroll
        for (int r = 0; r < 4; ++r)
          Sb[(size_t)task * (Kk * Vv) + (size_t)(w * 64 + i * 16 + fq * 4 + r) * Vv +
             vb4 * 64 + j * 16 + fr] = f2b(acc[i][j][r]);
  }
}

// ---------------- passR: sequential chunk recombine; 64k x 32v tiles (256 blocks) ----
__global__ __launch_bounds__(256) void passR_kernel(
    const unsigned short* __restrict__ Sb, const float* __restrict__ Dendb,
    unsigned short* __restrict__ S0Tb, float* __restrict__ state_out) {
  const int vt = blockIdx.x, kt = blockIdx.y, b = blockIdx.z;
  const int tid = threadIdx.x;
  const int kq = tid >> 2;
  const int vq = tid & 3;
  const int vr = tid >> 3;
  const int kqq = tid & 7;
  __shared__ __align__(16) unsigned short Ts[32][72];
  float st[8];
#pragma unroll
  for (int j = 0; j < 8; ++j) st[j] = 0.f;
  for (int c = 0; c < NC; ++c) {
    const int task = b * NC + c;
#pragma unroll
    for (int j = 0; j < 8; ++j) Ts[vq * 8 + j][kq] = f2b(st[j]);
    __syncthreads();
    {
      unsigned short* dst = S0Tb + (size_t)task * (Kk * Vv) +
                            (size_t)(vt * 32 + vr) * Kk + kt * 64 + kqq * 8;
      *(uint4*)dst = *(const uint4*)&Ts[vr][kqq * 8];
    }
    __syncthreads();
    const float d = Dendb[task * 256 + kt * 64 + kq];
    const unsigned short* sp = Sb + (size_t)task * (Kk * Vv) +
                               (size_t)(kt * 64 + kq) * Vv + vt * 32 + vq * 8;
    uint4 raw = *(const uint4*)sp;
    unsigned ws_[4] = {raw.x, raw.y, raw.z, raw.w};
#pragma unroll
    for (int e = 0; e < 4; ++e) {
      float lo = __uint_as_float(ws_[e] << 16);
      float hi = __uint_as_float(ws_[e] & 0xFFFF0000u);
      st[e * 2]     = d * st[e * 2] + lo;
      st[e * 2 + 1] = d * st[e * 2 + 1] + hi;
    }
  }
  float* so = state_out + (size_t)(b * Kk + kt * 64 + kq) * Vv + vt * 32 + vq * 8;
#pragma unroll
  for (int j = 0; j < 8; ++j) so[j] = st[j];
}

// ---------------- passO: per (b,c): att = q2*S0 + tril(A)*v ----------------
__global__ __launch_bounds__(256) void passO_kernel(
    const unsigned short* __restrict__ qab, const unsigned short* __restrict__ kab,
    const unsigned short* __restrict__ q2b, const float* __restrict__ LBb,
    const unsigned short* __restrict__ S0Tb, const unsigned short* __restrict__ vTb,
    unsigned short* __restrict__ attb) {
  const int c = blockIdx.x, b = blockIdx.y;
  const int task = b * NC + c;
  const int tid = threadIdx.x, lane = tid & 63, w = tid >> 6;
  const int fr = lane & 15, fq = lane >> 4, fk = fq * 8;
  __shared__ float LB_s[4][256];
  __shared__ float D_s[6][256];
  __shared__ __align__(16) unsigned short A_s[64][72];
  const size_t tbase = (size_t)task * (CC * Kk);
  for (int idx = tid; idx < 1024; idx += 256) LB_s[idx >> 8][idx & 255] = LBb[(size_t)task * 1024 + idx];
  for (int idx = tid; idx < 64 * 72 / 2; idx += 256) ((unsigned*)A_s)[idx] = 0;
  __syncthreads();
  {
    const int kk = tid;
#pragma unroll
    for (int pi = 0; pi < 6; ++pi) {
      const int I = (pi >= 3) ? 3 : (pi >= 1) ? 2 : 1;
      const int J = pi - (I * (I - 1)) / 2;
      D_s[pi][kk] = exp2f(LB_s[I][kk] - LB_s[J][kk]);
    }
  }
  __syncthreads();
  for (int p = w; p < 10; p += 4) {
    const int I = (p >= 6) ? 3 : (p >= 3) ? 2 : (p >= 1) ? 1 : 0;
    const int J = p - (I * (I + 1)) / 2;
    const int pidx = (I * (I - 1)) / 2 + J;
    f32x4 acc = {0.f, 0.f, 0.f, 0.f};
#pragma unroll
    for (int ks = 0; ks < 8; ++ks) {
      const int k0 = ks * 32 + fk;
      bf16x8 af = *(const bf16x8*)(qab + tbase + (size_t)(I * 16 + fr) * Kk + k0);
      if (I != J) {
#pragma unroll
        for (int e = 0; e < 8; ++e)
          af[e] = (__bf16)((float)af[e] * D_s[pidx][k0 + e]);
      }
      bf16x8 bf = *(const bf16x8*)(kab + tbase + (size_t)(J * 16 + fr) * Kk + k0);
      acc = __builtin_amdgcn_mfma_f32_16x16x32_bf16(af, bf, acc, 0, 0, 0);
    }
#pragma unroll
    for (int r = 0; r < 4; ++r) {
      const int ml = fq * 4 + r, nl = fr;
      bool keep = (I != J) || (nl <= ml);
      A_s[I * 16 + ml][J * 16 + nl] = keep ? f2b(acc[r]) : (unsigned short)0;
    }
  }
  __syncthreads();
  f32x4 acc2[4][4] = {};
  const unsigned short* q2t = q2b + tbase;
  const unsigned short* s0t = S0Tb + (size_t)task * (Kk * Vv);
  const unsigned short* vtp = vTb + (size_t)b * (Vv * Tt) + (size_t)c * CC;
  const int vbase = w * 64;
#pragma unroll
  for (int ks = 0; ks < 8; ++ks) {
    const int k0 = ks * 32 + fk;
    bf16x8 af[4], bf[4];
#pragma unroll
    for (int i = 0; i < 4; ++i) af[i] = *(const bf16x8*)(q2t + (size_t)(i * 16 + fr) * Kk + k0);
#pragma unroll
    for (int j = 0; j < 4; ++j) bf[j] = *(const bf16x8*)(s0t + (size_t)(vbase + j * 16 + fr) * Kk + k0);
#pragma unroll
    for (int i = 0; i < 4; ++i)
#pragma unroll
      for (int j = 0; j < 4; ++j)
        acc2[i][j] = __builtin_amdgcn_mfma_f32_16x16x32_bf16(af[i], bf[j], acc2[i][j], 0, 0, 0);
  }
#pragma unroll
  for (int ks = 0; ks < 2; ++ks) {
    const int s0 = ks * 32 + fk;
    bf16x8 af[4], bf[4];
#pragma unroll
    for (int i = 0; i < 4; ++i) af[i] = *(const bf16x8*)&A_s[i * 16 + fr][s0];
#pragma unroll
    for (int j = 0; j < 4; ++j) bf[j] = *(const bf16x8*)(vtp + (size_t)(vbase + j * 16 + fr) * Tt + s0);
#pragma unroll
    for (int i = 0; i < 4; ++i)
#pragma unroll
      for (int j = 0; j < 4; ++j)
        acc2[i][j] = __builtin_amdgcn_mfma_f32_16x16x32_bf16(af[i], bf[j], acc2[i][j], 0, 0, 0);
  }
#pragma unroll
  for (int i = 0; i < 4; ++i)
#pragma unroll
    for (int j = 0; j < 4; ++j)
#pragma unroll
      for (int r = 0; r < 4; ++r)
        attb[((size_t)b * Tt + c * CC + i * 16 + fq * 4 + r) * Vv + vbase + j * 16 + fr]
            = f2b(acc2[i][j][r]);
}

extern "C" void kernel_launch(void* const* d_in, const int* in_sizes, int n_in,
                              void* d_out, int out_size, void* d_ws, size_t ws_size,
                              hipStream_t stream) {
  const float* hs = (const float*)d_in[0];
  const float* Wq = (const float*)d_in[1];
  const float* bq = (const float*)d_in[2];
  const float* Wk = (const float*)d_in[3];
  const float* bk = (const float*)d_in[4];
  const float* Wv = (const float*)d_in[5];
  const float* bv = (const float*)d_in[6];
  const float* Wg = (const float*)d_in[7];
  const float* bg = (const float*)d_in[8];
  const float* Wo = (const float*)d_in[9];
  const float* bo = (const float*)d_in[10];

  float* out = (float*)d_out;
  float* state_out = out + (size_t)Bb * Tt * Oo;

  char* p = (char*)d_ws;
  auto alloc = [&](size_t bytes) {
    char* r = p;
    p += (bytes + 255) & ~(size_t)255;
    return r;
  };
  unsigned short* hsb   = (unsigned short*)alloc((size_t)Bb * Tt * Hh * 2);   // 32MB
  unsigned short* WallT = (unsigned short*)alloc((size_t)1024 * Hh * 2);      // 2MB
  unsigned short* WoT   = (unsigned short*)alloc((size_t)Oo * Vv * 2);
  unsigned short* qb    = (unsigned short*)alloc((size_t)Bb * Tt * Kk * 2);   // 8MB each
  unsigned short* kb    = (unsigned short*)alloc((size_t)Bb * Tt * Kk * 2);
  unsigned short* lgb   = (unsigned short*)alloc((size_t)Bb * Tt * Kk * 2);   // f16
  unsigned short* vTb   = (unsigned short*)alloc((size_t)Bb * Vv * Tt * 2);
  unsigned short* attb  = (unsigned short*)alloc((size_t)Bb * Tt * Vv * 2);
  unsigned short* q2b   = (unsigned short*)alloc((size_t)Bb * Tt * Kk * 2);
  unsigned short* qab   = (unsigned short*)alloc((size_t)Bb * Tt * Kk * 2);
  unsigned short* kab   = (unsigned short*)alloc((size_t)Bb * Tt * Kk * 2);
  float*          LBb   = (float*)alloc((size_t)Bb * NC * 4 * Kk * 4);
  float*          Dendb = (float*)alloc((size_t)Bb * NC * Kk * 4);
  unsigned short* Sb    = (unsigned short*)alloc((size_t)Bb * NC * Kk * Vv * 2);  // 32MB
  unsigned short* S0Tb  = (unsigned short*)alloc((size_t)Bb * NC * Kk * Vv * 2);  // 32MB

  // 1) casts + weight transposes (4 proj weights batched into one launch)
  int n4 = Bb * Tt * Hh / 4;
  cast_bf16_kernel<<<(n4 + 255) / 256, 256, 0, stream>>>(hs, hsb, n4);
  transpose_cast4_kernel<<<dim3(Hh / 32, Kk / 32, 4), 256, 0, stream>>>(
      Wq, Wk, Wg, Wv, WallT, Hh, Kk);
  transpose_cast_kernel<<<dim3(Vv / 32, Oo / 32), 256, 0, stream>>>(Wo, WoT, Vv, Oo);

  // 2) fused projections: 128x256 tile GEMM; v written transposed to vT
  gemm_wide_kernel<0><<<dim3(1024 / BN, (Bb * Tt) / BM), 512, 0, stream>>>(
      hsb, WallT, bq, bk, bg, bv, nullptr, qb, kb, lgb, vTb, Bb * Tt, 1024, Hh);

  // 3) fused prep + per-chunk state GEMM
  prep_sgemm_kernel<<<dim3(NC, Bb), 256, 0, stream>>>(qb, kb, lgb, vTb, q2b, qab, kab,
                                                      LBb, Dendb, Sb);

  // 4) sequential chunk recombine -> S0T (pre-chunk states) + final state
  passR_kernel<<<dim3(Vv / 32, Kk / 64, Bb), 256, 0, stream>>>(Sb, Dendb, S0Tb, state_out);

  // 5) outputs: att = q2.S0 + tril(A).v
  passO_kernel<<<dim3(NC, Bb), 256, 0, stream>>>(qab, kab, q2b, LBb, S0Tb, vTb, attb);

  // 6) output projection: 128x256 tile GEMM, f32 out
  gemm_wide_kernel<1><<<dim3(Oo / BN, (Bb * Tt) / BM), 512, 0, stream>>>(
      attb, WoT, bo, nullptr, nullptr, nullptr, out, nullptr, nullptr, nullptr, nullptr,
      Bb * Tt, Oo, Vv);
}

// Round 18
// 218.337 us; speedup vs baseline: 1.2566x; 1.2566x over previous
//
#include <hip/hip_runtime.h>

// Problem dims (fixed by setup_inputs)
#define Bb 8
#define Tt 2048
#define Hh 1024
#define Kk 256
#define Vv 256
#define Oo 1024
#define CC 64   // chunk length
#define NC 32   // chunks per batch (Tt/CC)

typedef __attribute__((ext_vector_type(8))) __bf16 bf16x8;
typedef __attribute__((ext_vector_type(4))) float f32x4;

__device__ __forceinline__ unsigned short f2b(float f) {
  unsigned u = __float_as_uint(f);
  u = (u + 0x7FFFu + ((u >> 16) & 1u)) >> 16;
  return (unsigned short)u;
}
__device__ __forceinline__ float b2f(unsigned short u) {
  return __uint_as_float(((unsigned)u) << 16);
}
__device__ __forceinline__ void gload_lds16(const unsigned short* g, unsigned short* l) {
  __builtin_amdgcn_global_load_lds(
      (const __attribute__((address_space(1))) void*)g,
      (__attribute__((address_space(3))) void*)l, 16, 0, 0);
}

// ---------------- cast f32 -> bf16 (vectorized) ----------------
__global__ __launch_bounds__(256) void cast_bf16_kernel(const float* __restrict__ in,
                                                        unsigned short* __restrict__ out,
                                                        int n4) {
  int i = blockIdx.x * 256 + threadIdx.x;
  if (i >= n4) return;
  float4 v = ((const float4*)in)[i];
  ushort4 o;
  o.x = f2b(v.x); o.y = f2b(v.y); o.z = f2b(v.z); o.w = f2b(v.w);
  ((ushort4*)out)[i] = o;
}

// ---------------- transpose + cast: W (H x N) f32 -> WT (N x H) bf16 ----------------
__global__ __launch_bounds__(256) void transpose_cast_kernel(const float* __restrict__ W,
                                                             unsigned short* __restrict__ WT,
                                                             int H, int N) {
  __shared__ float tile[32][33];
  int h0 = blockIdx.x * 32, n0 = blockIdx.y * 32;
  int tx = threadIdx.x & 31, ty = threadIdx.x >> 5;
  for (int r = ty; r < 32; r += 8)
    tile[r][tx] = W[(size_t)(h0 + r) * N + n0 + tx];
  __syncthreads();
  for (int r = ty; r < 32; r += 8)
    WT[(size_t)(n0 + r) * H + h0 + tx] = f2b(tile[tx][r]);
}

// ---------------- GEMM: 128x128, BK=64, 4 waves, swizzled LDS, 4 blocks/CU ----
// C = A (MxK) * Bt^T
// MODE 0: proj epilogue (LDS-staged coalesced writes; v-panel written transposed to vT)
// MODE 1: f32 out + bias b0p
#define BM 128
#define BN 128
#define BK 64

template <int MODE>
__global__ __launch_bounds__(256, 4) void gemm_mf_kernel(
    const unsigned short* __restrict__ A, const unsigned short* __restrict__ Bt,
    const float* __restrict__ b0p, const float* __restrict__ b1p,
    const float* __restrict__ b2p, const float* __restrict__ b3p,
    float* __restrict__ Cf,
    unsigned short* __restrict__ O0, unsigned short* __restrict__ O1,
    unsigned short* __restrict__ O2, unsigned short* __restrict__ O3,
    int M, int N, int K) {
  // One 32 KiB LDS pool: As/Bs during the K loop, reused as the epilogue stage tile.
  __shared__ __align__(16) unsigned short shbuf[16384];
  unsigned short* As = shbuf;          // 128*64
  unsigned short* Bs = shbuf + 8192;   // 128*64
  const int tid = threadIdx.x;
  const int lane = tid & 63, wid = tid >> 6;        // 4 waves
  const int wm = wid >> 1, wn = wid & 1;            // 2x2 wave grid; wave = 64x64 out
  // XCD-LOCAL tile mapping: XCD (lin&7) owns contiguous m-panels; n iterated fastest.
  // The 8 n-tiles sharing an A-panel run concurrently on the SAME XCD -> A-panel
  // crosses L3 once, re-reads hit that XCD's L2.
  const int lin = blockIdx.x + blockIdx.y * gridDim.x;
  const int xcd = lin & 7;
  const int jj = lin >> 3;
  const int mpg = gridDim.y >> 3;                   // m-panels per XCD
  const int m0 = (xcd * mpg + jj / gridDim.x) * BM;
  const int n0 = (jj % gridDim.x) * BN;
  const int fr = lane & 15, fq = lane >> 4;
  // staging: per gload a wave writes 8 rows x 128B. Lane l -> row +(l>>3),
  // LDS 16B-chunk (l&7); global source chunk = (l&7) ^ (l>>3).
  const int srl = lane >> 3;
  const int scs = ((lane & 7) ^ srl) * 8;
  const unsigned short* gaBase = A + (size_t)(m0 + srl) * K + scs;
  const unsigned short* gbBase = Bt + (size_t)(n0 + srl) * K + scs;

  f32x4 acc[4][4] = {};
  const int nt = K / BK;
  for (int t = 0; t < nt; ++t) {
    const int k0 = t * BK;
    __syncthreads();  // previous iter's LDS reads done
#pragma unroll
    for (int inst = 0; inst < 4; ++inst) {
      const int rb = wid * 32 + inst * 8;
      gload_lds16(gaBase + (size_t)rb * K + k0, &As[rb * BK]);
      gload_lds16(gbBase + (size_t)rb * K + k0, &Bs[rb * BK]);
    }
    __syncthreads();  // staged data visible (drain hidden by co-resident blocks)
#pragma unroll
    for (int ks = 0; ks < 2; ++ks) {
      bf16x8 af[4], bfv[4];
#pragma unroll
      for (int j = 0; j < 4; ++j) {
        const int R = wn * 64 + j * 16 + fr;
        const int ch = ((ks << 2) | fq) ^ (fr & 7);
        bfv[j] = *(const bf16x8*)&Bs[R * BK + ch * 8];
      }
#pragma unroll
      for (int i = 0; i < 4; ++i) {
        const int R = wm * 64 + i * 16 + fr;
        const int ch = ((ks << 2) | fq) ^ (fr & 7);
        af[i] = *(const bf16x8*)&As[R * BK + ch * 8];
      }
#pragma unroll
      for (int i = 0; i < 4; ++i)
#pragma unroll
        for (int j = 0; j < 4; ++j)
          acc[i][j] = __builtin_amdgcn_mfma_f32_16x16x32_bf16(af[i], bfv[j], acc[i][j], 0, 0, 0);
    }
  }
  if (MODE == 1) {
    // simple epilogue: f32, 64B segments per 16-lane cluster (no amplification)
#pragma unroll
    for (int j = 0; j < 4; ++j) {
      const int n = n0 + wn * 64 + j * 16 + fr;
      const float bv = b0p[n];
#pragma unroll
      for (int i = 0; i < 4; ++i) {
        const int mb = m0 + wm * 64 + i * 16 + fq * 4;
#pragma unroll
        for (int r = 0; r < 4; ++r)
          Cf[(size_t)(mb + r) * N + n] = acc[i][j][r] + bv;
      }
    }
  } else {
    // LDS-staged epilogue: transform in reg, stage bf16/f16 tile (XOR-chunk swizzle),
    // then write 256B-contiguous rows with dwordx4 (kills 2x write amplification).
    __syncthreads();  // all waves done reading As/Bs before reuse
    const int sel = n0 >> 8;
    const float* bp = sel == 0 ? b0p : sel == 1 ? b1p : sel == 2 ? b2p : b3p;
#pragma unroll
    for (int j = 0; j < 4; ++j) {
      const int ncol = wn * 64 + j * 16 + fr;       // tile-local col [0,128)
      const int nloc = (n0 & 255) + ncol;           // panel-local col [0,256)
      const float bv = bp[nloc];
#pragma unroll
      for (int i = 0; i < 4; ++i) {
#pragma unroll
        for (int r = 0; r < 4; ++r) {
          const int ml = wm * 64 + i * 16 + fq * 4 + r;
          const float x = acc[i][j][r] + bv;
          unsigned short us;
          if (sel == 0) {
            us = f2b(x);
          } else if (sel == 1) {
            us = f2b(1.f / (1.f + expf(-x)));
          } else if (sel == 2) {
            float e = exp2f(-x * 1.44269504f);
            float lg = -log2f(1.f + e);
            _Float16 hv = (_Float16)lg;
            __builtin_memcpy(&us, &hv, 2);
          } else {
            us = f2b(x);
          }
          if (sel == 3) {  // stage transposed: row = v (ncol), col = t (ml)
            const int cm = (ml >> 3) ^ (ncol & 15);
            shbuf[ncol * 128 + cm * 8 + (ml & 7)] = us;
          } else {         // row = m (ml), col = n (ncol)
            const int cn = (ncol >> 3) ^ (ml & 15);
            shbuf[ml * 128 + cn * 8 + (ncol & 7)] = us;
          }
        }
      }
    }
    __syncthreads();
    // write out: 128 rows x 256B; 2 threads/row, 8 x 16B stores each
    const int row = tid >> 1;
    const int half = tid & 1;
    if (sel == 3) {
      unsigned short* dst = O3 + ((size_t)(m0 >> 11) * Vv + (n0 & 255) + row) * Tt +
                            (m0 & 2047) + half * 64;
#pragma unroll
      for (int ic = 0; ic < 8; ++ic) {
        const int chunk = half * 8 + ic;
        const int sc = chunk ^ (row & 15);
        *(uint4*)(dst + ic * 8) = *(const uint4*)&shbuf[row * 128 + sc * 8];
      }
    } else {
      unsigned short* Op = sel == 0 ? O0 : sel == 1 ? O1 : O2;
      unsigned short* dst = Op + (size_t)(m0 + row) * 256 + (n0 & 255) + half * 64;
#pragma unroll
      for (int ic = 0; ic < 8; ++ic) {
        const int chunk = half * 8 + ic;
        const int sc = chunk ^ (row & 15);
        *(uint4*)(dst + ic * 8) = *(const uint4*)&shbuf[row * 128 + sc * 8];
      }
    }
  }
}

// ---------------- fused prep+sgemm: per (b,c) task ----------------
__global__ __launch_bounds__(256) void prep_sgemm_kernel(
    const unsigned short* __restrict__ qb, const unsigned short* __restrict__ kb,
    const unsigned short* __restrict__ lgb, const unsigned short* __restrict__ vTb,
    unsigned short* __restrict__ q2b, unsigned short* __restrict__ qab,
    unsigned short* __restrict__ kab,
    float* __restrict__ LBb, float* __restrict__ Dendb,
    unsigned short* __restrict__ Sb) {
  __shared__ __align__(16) unsigned short khs[256][72];
  const int c = blockIdx.x, b = blockIdx.y;
  const int k = threadIdx.x;
  const int task = b * NC + c;
  const size_t rowbase = ((size_t)b * Tt + (size_t)c * CC) * Kk + k;
  float Ls = 0.f;
  float LBr[4];
#pragma unroll
  for (int gq = 0; gq < 4; ++gq) {
    LBr[gq] = Ls;
#pragma unroll
    for (int tt = 0; tt < 16; ++tt) {
      int t = gq * 16 + tt;
      _Float16 hv;
      __builtin_memcpy(&hv, &lgb[rowbase + (size_t)t * Kk], 2);
      Ls += (float)hv;
    }
  }
  const float Lend = Ls;
#pragma unroll
  for (int gq = 0; gq < 4; ++gq) LBb[(size_t)task * 1024 + gq * 256 + k] = LBr[gq];
  Dendb[task * 256 + k] = exp2f(Lend);
  float L = 0.f;
#pragma unroll
  for (int gq = 0; gq < 4; ++gq) {
    const float LBc = LBr[gq];
    unsigned kw[8];
#pragma unroll
    for (int tt = 0; tt < 16; ++tt) {
      int t = gq * 16 + tt;
      size_t off = rowbase + (size_t)t * Kk;
      _Float16 hv;
      __builtin_memcpy(&hv, &lgb[off], 2);
      L += (float)hv;
      float qv = b2f(qb[off]);
      float kv = b2f(kb[off]);
      q2b[off] = f2b(qv * exp2f(L));
      qab[off] = f2b(qv * exp2f(L - LBc));
      kab[off] = f2b(kv * exp2f(LBc - L));
      unsigned short kh = f2b(kv * exp2f(Lend - L));
      if (tt & 1) kw[tt >> 1] |= ((unsigned)kh) << 16;
      else        kw[tt >> 1] = kh;
    }
    uint4 u0; u0.x = kw[0]; u0.y = kw[1]; u0.z = kw[2]; u0.w = kw[3];
    uint4 u1; u1.x = kw[4]; u1.y = kw[5]; u1.z = kw[6]; u1.w = kw[7];
    *(uint4*)&khs[k][gq * 16] = u0;
    *(uint4*)&khs[k][gq * 16 + 8] = u1;
  }
  __syncthreads();
  const int tid = threadIdx.x, lane = tid & 63, w = tid >> 6;
  const int fr = lane & 15, fq = lane >> 4, fk = fq * 8;
  const unsigned short* vt = vTb + (size_t)b * (Vv * Tt) + (size_t)c * CC;
  for (int vb4 = 0; vb4 < 4; ++vb4) {
    f32x4 acc[4][4] = {};
#pragma unroll
    for (int ks = 0; ks < 2; ++ks) {
      bf16x8 af[4], bf[4];
#pragma unroll
      for (int i = 0; i < 4; ++i)
        af[i] = *(const bf16x8*)&khs[w * 64 + i * 16 + fr][ks * 32 + fk];
#pragma unroll
      for (int j = 0; j < 4; ++j)
        bf[j] = *(const bf16x8*)(vt + (size_t)(vb4 * 64 + j * 16 + fr) * Tt + ks * 32 + fk);
#pragma unroll
      for (int i = 0; i < 4; ++i)
#pragma unroll
        for (int j = 0; j < 4; ++j)
          acc[i][j] = __builtin_amdgcn_mfma_f32_16x16x32_bf16(af[i], bf[j], acc[i][j], 0, 0, 0);
    }
#pragma unroll
    for (int i = 0; i < 4; ++i)
#pragma unroll
      for (int j = 0; j < 4; ++j)
#pragma unroll
        for (int r = 0; r < 4; ++r)
          Sb[(size_t)task * (Kk * Vv) + (size_t)(w * 64 + i * 16 + fq * 4 + r) * Vv +
             vb4 * 64 + j * 16 + fr] = f2b(acc[i][j][r]);
  }
}

// ---------------- passR: sequential chunk recombine; 64k x 32v tiles (256 blocks) ----
__global__ __launch_bounds__(256) void passR_kernel(
    const unsigned short* __restrict__ Sb, const float* __restrict__ Dendb,
    unsigned short* __restrict__ S0Tb, float* __restrict__ state_out) {
  const int vt = blockIdx.x, kt = blockIdx.y, b = blockIdx.z;  // (8, 4, 8)
  const int tid = threadIdx.x;
  const int kq = tid >> 2;     // k_local 0..63
  const int vq = tid & 3;      // v group (8 v each)
  const int vr = tid >> 3;     // write-phase: v row 0..31
  const int kqq = tid & 7;     // write-phase: k group (8 k each)
  __shared__ __align__(16) unsigned short Ts[32][72];
  float st[8];
#pragma unroll
  for (int j = 0; j < 8; ++j) st[j] = 0.f;
  for (int c = 0; c < NC; ++c) {
    const int task = b * NC + c;
#pragma unroll
    for (int j = 0; j < 8; ++j) Ts[vq * 8 + j][kq] = f2b(st[j]);
    __syncthreads();
    {
      unsigned short* dst = S0Tb + (size_t)task * (Kk * Vv) +
                            (size_t)(vt * 32 + vr) * Kk + kt * 64 + kqq * 8;
      *(uint4*)dst = *(const uint4*)&Ts[vr][kqq * 8];
    }
    __syncthreads();
    const float d = Dendb[task * 256 + kt * 64 + kq];
    const unsigned short* sp = Sb + (size_t)task * (Kk * Vv) +
                               (size_t)(kt * 64 + kq) * Vv + vt * 32 + vq * 8;
    uint4 raw = *(const uint4*)sp;
    unsigned ws_[4] = {raw.x, raw.y, raw.z, raw.w};
#pragma unroll
    for (int e = 0; e < 4; ++e) {
      float lo = __uint_as_float(ws_[e] << 16);
      float hi = __uint_as_float(ws_[e] & 0xFFFF0000u);
      st[e * 2]     = d * st[e * 2] + lo;
      st[e * 2 + 1] = d * st[e * 2 + 1] + hi;
    }
  }
  float* so = state_out + (size_t)(b * Kk + kt * 64 + kq) * Vv + vt * 32 + vq * 8;
#pragma unroll
  for (int j = 0; j < 8; ++j) so[j] = st[j];
}

// ---------------- passO: per (b,c): att = q2*S0 + tril(A)*v ----------------
__global__ __launch_bounds__(256) void passO_kernel(
    const unsigned short* __restrict__ qab, const unsigned short* __restrict__ kab,
    const unsigned short* __restrict__ q2b, const float* __restrict__ LBb,
    const unsigned short* __restrict__ S0Tb, const unsigned short* __restrict__ vTb,
    unsigned short* __restrict__ attb) {
  const int c = blockIdx.x, b = blockIdx.y;
  const int task = b * NC + c;
  const int tid = threadIdx.x, lane = tid & 63, w = tid >> 6;
  const int fr = lane & 15, fq = lane >> 4, fk = fq * 8;
  __shared__ float LB_s[4][256];
  __shared__ float D_s[6][256];   // pair (I>J) scale factors: pidx = I*(I-1)/2 + J
  __shared__ __align__(16) unsigned short A_s[64][72];
  const size_t tbase = (size_t)task * (CC * Kk);
  for (int idx = tid; idx < 1024; idx += 256) LB_s[idx >> 8][idx & 255] = LBb[(size_t)task * 1024 + idx];
  for (int idx = tid; idx < 64 * 72 / 2; idx += 256) ((unsigned*)A_s)[idx] = 0;
  __syncthreads();
  // precompute pair scales (value depends only on k -> compute once, not per-lane-row)
  {
    const int kk = tid;
#pragma unroll
    for (int pi = 0; pi < 6; ++pi) {
      const int I = (pi >= 3) ? 3 : (pi >= 1) ? 2 : 1;
      const int J = pi - (I * (I - 1)) / 2;
      D_s[pi][kk] = exp2f(LB_s[I][kk] - LB_s[J][kk]);
    }
  }
  __syncthreads();
  for (int p = w; p < 10; p += 4) {
    const int I = (p >= 6) ? 3 : (p >= 3) ? 2 : (p >= 1) ? 1 : 0;
    const int J = p - (I * (I + 1)) / 2;
    const int pidx = (I * (I - 1)) / 2 + J;  // valid when I != J
    f32x4 acc = {0.f, 0.f, 0.f, 0.f};
#pragma unroll
    for (int ks = 0; ks < 8; ++ks) {
      const int k0 = ks * 32 + fk;
      bf16x8 af = *(const bf16x8*)(qab + tbase + (size_t)(I * 16 + fr) * Kk + k0);
      if (I != J) {
#pragma unroll
        for (int e = 0; e < 8; ++e)
          af[e] = (__bf16)((float)af[e] * D_s[pidx][k0 + e]);
      }
      bf16x8 bf = *(const bf16x8*)(kab + tbase + (size_t)(J * 16 + fr) * Kk + k0);
      acc = __builtin_amdgcn_mfma_f32_16x16x32_bf16(af, bf, acc, 0, 0, 0);
    }
#pragma unroll
    for (int r = 0; r < 4; ++r) {
      const int ml = fq * 4 + r, nl = fr;
      bool keep = (I != J) || (nl <= ml);
      A_s[I * 16 + ml][J * 16 + nl] = keep ? f2b(acc[r]) : (unsigned short)0;
    }
  }
  __syncthreads();
  f32x4 acc2[4][4] = {};
  const unsigned short* q2t = q2b + tbase;
  const unsigned short* s0t = S0Tb + (size_t)task * (Kk * Vv);
  const unsigned short* vtp = vTb + (size_t)b * (Vv * Tt) + (size_t)c * CC;
  const int vbase = w * 64;
#pragma unroll
  for (int ks = 0; ks < 8; ++ks) {
    const int k0 = ks * 32 + fk;
    bf16x8 af[4], bf[4];
#pragma unroll
    for (int i = 0; i < 4; ++i) af[i] = *(const bf16x8*)(q2t + (size_t)(i * 16 + fr) * Kk + k0);
#pragma unroll
    for (int j = 0; j < 4; ++j) bf[j] = *(const bf16x8*)(s0t + (size_t)(vbase + j * 16 + fr) * Kk + k0);
#pragma unroll
    for (int i = 0; i < 4; ++i)
#pragma unroll
      for (int j = 0; j < 4; ++j)
        acc2[i][j] = __builtin_amdgcn_mfma_f32_16x16x32_bf16(af[i], bf[j], acc2[i][j], 0, 0, 0);
  }
#pragma unroll
  for (int ks = 0; ks < 2; ++ks) {
    const int s0 = ks * 32 + fk;
    bf16x8 af[4], bf[4];
#pragma unroll
    for (int i = 0; i < 4; ++i) af[i] = *(const bf16x8*)&A_s[i * 16 + fr][s0];
#pragma unroll
    for (int j = 0; j < 4; ++j) bf[j] = *(const bf16x8*)(vtp + (size_t)(vbase + j * 16 + fr) * Tt + s0);
#pragma unroll
    for (int i = 0; i < 4; ++i)
#pragma unroll
      for (int j = 0; j < 4; ++j)
        acc2[i][j] = __builtin_amdgcn_mfma_f32_16x16x32_bf16(af[i], bf[j], acc2[i][j], 0, 0, 0);
  }
#pragma unroll
  for (int i = 0; i < 4; ++i)
#pragma unroll
    for (int j = 0; j < 4; ++j)
#pragma unroll
      for (int r = 0; r < 4; ++r)
        attb[((size_t)b * Tt + c * CC + i * 16 + fq * 4 + r) * Vv + vbase + j * 16 + fr]
            = f2b(acc2[i][j][r]);
}

extern "C" void kernel_launch(void* const* d_in, const int* in_sizes, int n_in,
                              void* d_out, int out_size, void* d_ws, size_t ws_size,
                              hipStream_t stream) {
  const float* hs = (const float*)d_in[0];
  const float* Wq = (const float*)d_in[1];
  const float* bq = (const float*)d_in[2];
  const float* Wk = (const float*)d_in[3];
  const float* bk = (const float*)d_in[4];
  const float* Wv = (const float*)d_in[5];
  const float* bv = (const float*)d_in[6];
  const float* Wg = (const float*)d_in[7];
  const float* bg = (const float*)d_in[8];
  const float* Wo = (const float*)d_in[9];
  const float* bo = (const float*)d_in[10];

  float* out = (float*)d_out;
  float* state_out = out + (size_t)Bb * Tt * Oo;

  char* p = (char*)d_ws;
  auto alloc = [&](size_t bytes) {
    char* r = p;
    p += (bytes + 255) & ~(size_t)255;
    return r;
  };
  unsigned short* hsb   = (unsigned short*)alloc((size_t)Bb * Tt * Hh * 2);   // 32MB
  unsigned short* WallT = (unsigned short*)alloc((size_t)1024 * Hh * 2);      // 2MB
  unsigned short* WoT   = (unsigned short*)alloc((size_t)Oo * Vv * 2);
  unsigned short* qb    = (unsigned short*)alloc((size_t)Bb * Tt * Kk * 2);   // 8MB each
  unsigned short* kb    = (unsigned short*)alloc((size_t)Bb * Tt * Kk * 2);
  unsigned short* lgb   = (unsigned short*)alloc((size_t)Bb * Tt * Kk * 2);   // f16
  unsigned short* vTb   = (unsigned short*)alloc((size_t)Bb * Vv * Tt * 2);
  unsigned short* attb  = (unsigned short*)alloc((size_t)Bb * Tt * Vv * 2);
  unsigned short* q2b   = (unsigned short*)alloc((size_t)Bb * Tt * Kk * 2);
  unsigned short* qab   = (unsigned short*)alloc((size_t)Bb * Tt * Kk * 2);
  unsigned short* kab   = (unsigned short*)alloc((size_t)Bb * Tt * Kk * 2);
  float*          LBb   = (float*)alloc((size_t)Bb * NC * 4 * Kk * 4);
  float*          Dendb = (float*)alloc((size_t)Bb * NC * Kk * 4);
  unsigned short* Sb    = (unsigned short*)alloc((size_t)Bb * NC * Kk * Vv * 2);  // 32MB
  unsigned short* S0Tb  = (unsigned short*)alloc((size_t)Bb * NC * Kk * Vv * 2);  // 32MB

  // 1) casts + weight transposes (concat projection weights into WallT rows)
  int n4 = Bb * Tt * Hh / 4;
  cast_bf16_kernel<<<(n4 + 255) / 256, 256, 0, stream>>>(hs, hsb, n4);
  transpose_cast_kernel<<<dim3(Hh / 32, Kk / 32), 256, 0, stream>>>(Wq, WallT + 0 * Kk * Hh, Hh, Kk);
  transpose_cast_kernel<<<dim3(Hh / 32, Kk / 32), 256, 0, stream>>>(Wk, WallT + 1 * Kk * Hh, Hh, Kk);
  transpose_cast_kernel<<<dim3(Hh / 32, Kk / 32), 256, 0, stream>>>(Wg, WallT + 2 * Kk * Hh, Hh, Kk);
  transpose_cast_kernel<<<dim3(Hh / 32, Kk / 32), 256, 0, stream>>>(Wv, WallT + 3 * Kk * Hh, Hh, Kk);
  transpose_cast_kernel<<<dim3(Vv / 32, Oo / 32), 256, 0, stream>>>(Wo, WoT, Vv, Oo);

  // 2) fused projections: 128^2 tiles, N=1024; v written directly transposed to vT
  gemm_mf_kernel<0><<<dim3(1024 / BN, (Bb * Tt) / BM), 256, 0, stream>>>(
      hsb, WallT, bq, bk, bg, bv, nullptr, qb, kb, lgb, vTb, Bb * Tt, 1024, Hh);

  // 3) fused prep + per-chunk state GEMM
  prep_sgemm_kernel<<<dim3(NC, Bb), 256, 0, stream>>>(qb, kb, lgb, vTb, q2b, qab, kab,
                                                      LBb, Dendb, Sb);

  // 4) sequential chunk recombine -> S0T (pre-chunk states) + final state
  passR_kernel<<<dim3(Vv / 32, Kk / 64, Bb), 256, 0, stream>>>(Sb, Dendb, S0Tb, state_out);

  // 5) outputs: att = q2.S0 + tril(A).v
  passO_kernel<<<dim3(NC, Bb), 256, 0, stream>>>(qab, kab, q2b, LBb, S0Tb, vTb, attb);

  // 6) output projection: pipelined 128^2 kernel, f32 out
  gemm_mf_kernel<1><<<dim3(Oo / BN, (Bb * Tt) / BM), 256, 0, stream>>>(
      attb, WoT, bo, nullptr, nullptr, nullptr, out, nullptr, nullptr, nullptr, nullptr,
      Bb * Tt, Oo, Vv);
}